// Round 3
// baseline (491.898 us; speedup 1.0000x reference)
//
#include <hip/hip_runtime.h>
#include <cstdint>
#include <cstddef>

// Problem constants: x[8192,4096]f32, Wp[4096,2048]i32(1 byte each),
// scales[4096,32]f32, group=128, out[8192,4096]f32.
#define TOKENS 8192
#define IN_F   4096
#define OUT_F  4096

typedef __bf16 bf16;
typedef bf16  bf16x8  __attribute__((ext_vector_type(8)));
typedef float f32x16  __attribute__((ext_vector_type(16)));

// ---------------- merged pre-pass: x f32->bf16 AND int4 W -> bf16 ----------------
// grid-stride, 2048 blocks x 256: 8 iters for x, 4 for W. BW-bound either way;
// fewer dispatch rounds than the 24576-block one-shot version.
__global__ void prep_kernel(const float* __restrict__ xin, bf16* __restrict__ xout,
                            const int* __restrict__ wp, const float* __restrict__ sc,
                            bf16* __restrict__ wout) {
    const int nth = gridDim.x * 256;
    const int t0  = blockIdx.x * 256 + threadIdx.x;
    for (int i = t0; i < TOKENS * IN_F / 8; i += nth) {
        size_t off = (size_t)i * 8;
        const float4* p = (const float4*)(xin + off);
        float4 a = p[0], b = p[1];
        bf16x8 r;
        r[0] = (bf16)a.x; r[1] = (bf16)a.y; r[2] = (bf16)a.z; r[3] = (bf16)a.w;
        r[4] = (bf16)b.x; r[5] = (bf16)b.y; r[6] = (bf16)b.z; r[7] = (bf16)b.w;
        *(bf16x8*)(xout + off) = r;
    }
    for (int t = t0; t < OUT_F * IN_F / 8; t += nth) {
        int j0 = t << 2;                    // first packed byte index
        int n  = j0 >> 11;
        int g  = (j0 & 2047) >> 6;
        float s = sc[(n << 5) + g];
        int4 p = *(const int4*)(wp + j0);
        bf16x8 r;
        r[0] = (bf16)((float)((p.x & 15) - 8) * s);
        r[1] = (bf16)((float)(((p.x >> 4) & 15) - 8) * s);
        r[2] = (bf16)((float)((p.y & 15) - 8) * s);
        r[3] = (bf16)((float)(((p.y >> 4) & 15) - 8) * s);
        r[4] = (bf16)((float)((p.z & 15) - 8) * s);
        r[5] = (bf16)((float)(((p.z >> 4) & 15) - 8) * s);
        r[6] = (bf16)((float)((p.w & 15) - 8) * s);
        r[7] = (bf16)((float)(((p.w >> 4) & 15) - 8) * s);
        *(bf16x8*)(wout + ((size_t)j0 << 1)) = r;
    }
}

// ---------------- main GEMM: 256x256 tile, BK=64, 4-phase/K-tile, 32x32x16 MFMA ----------------
// 512 threads = 8 waves (2M x 4N); per-wave 128x64 output = 4x2 tiles of 32x32.
// 32x32x16 runs at 2495 TF vs 2176 for 16x16x32 (m119): same LDS fragment traffic
// (24 x ds_read_b128 / wave / K-tile), ~17% fewer matrix-pipe busy cycles.
// LDS 128 KiB double buffer, XOR chunk swizzle on the GLOBAL source side (dests linear).
//
// Phase p = [ds_reads(p) | 1 stage | (vmcnt at ph3) | s_barrier+sched_barrier(0) |
//            8 MFMA setprio-wrapped]. One barrier per phase (WAR-safe: a wave passes
// BAR(p) only after MM(p-1) consumed its reads; every stage is issued >=1 barrier
// after its region's consuming phase).
//
// Region read phase: A0 {rows 0-63,128-191}: ph0 | B0 {row&32==0}: ph0 |
//                    B1 {row&32==1}: ph1 | A1 {rows 64-127,192-255}: ph2
// Stage slots: ph0: B1(next tile, other buf) | ph1: A1(next, other buf) |
//              ph2: A0(tile+2, this buf) | ph3: B0(tile+2, this buf) + vmcnt(4)
// vmcnt(4) once/tile: forces tile+1 fully landed, keeps A0/B0 of tile+2 in flight.
//
// Fragment lane-maps (32x32x16 bf16):
//   A/B input: row(col)=lane&31, k = 8*(lane>>5)+e  [canonical ext. of 32x32x8]
//   C/D:       col=lane&31, row=(reg&3)+8*(reg>>2)+4*(lane>>5)  [m74/m101-verified]

#define GLL(src, dst) __builtin_amdgcn_global_load_lds( \
    (const __attribute__((address_space(1))) void*)(src), \
    (__attribute__((address_space(3))) void*)(dst), 16, 0, 0)
#define BARX() { __builtin_amdgcn_s_barrier(); __builtin_amdgcn_sched_barrier(0); }

__global__ __launch_bounds__(512, 2)
void gemm_kernel(const bf16* __restrict__ A, const bf16* __restrict__ B,
                 float* __restrict__ C) {
    __shared__ char smem[131072] __attribute__((aligned(128)));

    const int tid  = threadIdx.x;
    const int lane = tid & 63;
    const int w    = tid >> 6;
    const int wr   = w >> 2, wc = w & 3;
    const int lrow = lane >> 3;             // row within the wave's 8-row stage block
    const int gsw  = (lane & 7) ^ lrow;     // pre-swizzled global chunk within 128B row

    // bijective XCD swizzle (512 % 8 == 0)
    const int wg = ((blockIdx.x & 7) << 6) | (blockIdx.x >> 3);
    const int mt = wg >> 4;                 // 32 M-tiles
    const int nt = wg & 15;                 // 16 N-tiles

    const char* Abase = (const char*)A + (size_t)(mt * 256) * (IN_F * 2);
    const char* Bbase = (const char*)B + (size_t)(nt * 256) * (IN_F * 2);

    const char* gA[4];
#pragma unroll
    for (int t = 0; t < 4; ++t)
        gA[t] = Abase + (size_t)(t * 64 + w * 8 + lrow) * (IN_F * 2) + gsw * 16;
    const int rb = (w >> 2) * 64 + (w & 3) * 8;
    const int brow0 = rb, brow1 = rb + 128, brow2 = rb + 32, brow3 = rb + 160;
    const char* gB[4];
    gB[0] = Bbase + (size_t)(brow0 + lrow) * (IN_F * 2) + gsw * 16;
    gB[1] = Bbase + (size_t)(brow1 + lrow) * (IN_F * 2) + gsw * 16;
    gB[2] = Bbase + (size_t)(brow2 + lrow) * (IN_F * 2) + gsw * 16;
    gB[3] = Bbase + (size_t)(brow3 + lrow) * (IN_F * 2) + gsw * 16;

    char* const sm = smem;
    // wave-uniform LDS dest bases (HW adds lane*16)
#define ST_A0(b, kt) { GLL(gA[0] + (kt) * 128, sm + (b) * 65536 +     0 + w * 1024); \
                       GLL(gA[2] + (kt) * 128, sm + (b) * 65536 + 16384 + w * 1024); }
#define ST_A1(b, kt) { GLL(gA[1] + (kt) * 128, sm + (b) * 65536 +  8192 + w * 1024); \
                       GLL(gA[3] + (kt) * 128, sm + (b) * 65536 + 24576 + w * 1024); }
#define ST_B0(b, kt) { GLL(gB[0] + (kt) * 128, sm + (b) * 65536 + 32768 + brow0 * 128); \
                       GLL(gB[1] + (kt) * 128, sm + (b) * 65536 + 32768 + brow1 * 128); }
#define ST_B1(b, kt) { GLL(gB[2] + (kt) * 128, sm + (b) * 65536 + 32768 + brow2 * 128); \
                       GLL(gB[3] + (kt) * 128, sm + (b) * 65536 + 32768 + brow3 * 128); }

    const int l31 = lane & 31, lhi = lane >> 5, sw7 = lane & 7;
    const bf16x8* pA0 = (const bf16x8*)sm;
    const bf16x8* pB0 = (const bf16x8*)(sm + 32768);
    const bf16x8* pA1 = (const bf16x8*)(sm + 65536);
    const bf16x8* pB1 = (const bf16x8*)(sm + 98304);

    f32x16 acc[4][2];
#pragma unroll
    for (int i = 0; i < 4; ++i)
#pragma unroll
        for (int j = 0; j < 2; ++j) acc[i][j] = (f32x16)0.0f;

    // prologue: tile0 fully; tile1's A0/B0; leave the 2 newest half-tiles in flight
    ST_A0(0, 0); ST_B0(0, 0); ST_B1(0, 0); ST_A1(0, 0);
    ST_A0(1, 1); ST_B0(1, 1);
    asm volatile("s_waitcnt vmcnt(4)" ::: "memory");
    __builtin_amdgcn_s_barrier();

    // A-frag: lane reads row (base + l31), 16B chunk (ks*2 + lhi), XOR-unswizzled
#define LDA32(dst, PA, qr) \
    { _Pragma("unroll") for (int mi = 0; mi < 2; ++mi) { \
        _Pragma("unroll") for (int ks = 0; ks < 4; ++ks) { \
            dst[mi][ks] = (PA)[(wr * 128 + (qr) * 64 + mi * 32 + l31) * 8 + ((ks * 2 + lhi) ^ sw7)]; } } }
#define LDB32(PB, nj) \
    { _Pragma("unroll") for (int ks = 0; ks < 4; ++ks) { \
        bfr[nj][ks] = (PB)[(wc * 64 + (nj) * 32 + l31) * 8 + ((ks * 2 + lhi) ^ sw7)]; } }
#define MM32(afv, qr, nj) \
    { __builtin_amdgcn_s_setprio(1); \
      _Pragma("unroll") for (int ks = 0; ks < 4; ++ks) { \
        _Pragma("unroll") for (int mi = 0; mi < 2; ++mi) { \
            acc[(qr) * 2 + mi][nj] = __builtin_amdgcn_mfma_f32_32x32x16_bf16( \
                afv[mi][ks], bfr[nj][ks], acc[(qr) * 2 + mi][nj], 0, 0, 0); } } \
      __builtin_amdgcn_s_setprio(0); }

    for (int it = 0; it < 32; ++it) {
        const int kt0 = 2 * it;
        const int kt1 = kt0 + 1;
        const bool more = (it < 31);
        {   // ---- tile kt0 from buf0 ----
            bf16x8 af0[2][4], af1[2][4], bfr[2][4];
            LDA32(af0, pA0, 0); LDB32(pB0, 0);     // ph0: 12 ds_read_b128
            ST_B1(1, kt1);                         //   buf1.B1 for tile kt1
            BARX(); MM32(af0, 0, 0);
            LDB32(pB0, 1);                         // ph1: 4 ds_read_b128
            ST_A1(1, kt1);                         //   buf1.A1
            BARX(); MM32(af0, 0, 1);
            LDA32(af1, pA0, 1);                    // ph2: 8 ds_read_b128
            if (more) ST_A0(0, kt0 + 2);           //   buf0.A0 (read-drained at ph0)
            BARX(); MM32(af1, 1, 0);
            if (more) {                            // ph3: no reads
                ST_B0(0, kt0 + 2);
                asm volatile("s_waitcnt vmcnt(4)" ::: "memory");
            } else {
                asm volatile("s_waitcnt vmcnt(0)" ::: "memory");
            }
            BARX(); MM32(af1, 1, 1);
        }
        {   // ---- tile kt1 from buf1 ----
            bf16x8 af0[2][4], af1[2][4], bfr[2][4];
            LDA32(af0, pA1, 0); LDB32(pB1, 0);     // ph0
            if (more) ST_B1(0, kt1 + 1);           //   buf0.B1 for tile kt1+1
            BARX(); MM32(af0, 0, 0);
            LDB32(pB1, 1);                         // ph1
            if (more) ST_A1(0, kt1 + 1);           //   buf0.A1
            BARX(); MM32(af0, 0, 1);
            LDA32(af1, pA1, 1);                    // ph2
            if (more) ST_A0(1, kt1 + 2);           //   buf1.A0
            BARX(); MM32(af1, 1, 0);
            if (more) {                            // ph3
                ST_B0(1, kt1 + 2);
                asm volatile("s_waitcnt vmcnt(4)" ::: "memory");
            }
            BARX(); MM32(af1, 1, 1);
        }
    }

    // epilogue: C/D layout col=lane&31, row=(reg&3)+8*(reg>>2)+4*(lane>>5)
    const size_t cbase = (size_t)(mt * 256 + wr * 128 + 4 * lhi) * OUT_F
                       + (size_t)(nt * 256 + wc * 64 + l31);
#pragma unroll
    for (int t = 0; t < 4; ++t)
#pragma unroll
        for (int nj = 0; nj < 2; ++nj) {
            float* cp = C + cbase + (size_t)(t * 32) * OUT_F + nj * 32;
#pragma unroll
            for (int rq = 0; rq < 4; ++rq)
#pragma unroll
                for (int rr = 0; rr < 4; ++rr)
                    cp[(size_t)(8 * rq + rr) * OUT_F] = acc[t][nj][rq * 4 + rr];
        }
}

// ---------------- fallback (only if ws too small): slow but correct ----------------
__global__ void naive_kernel(const float* __restrict__ x, const int* __restrict__ wp,
                             const float* __restrict__ sc, float* __restrict__ out) {
    int o = blockIdx.x * 256 + threadIdx.x;
    int t = o >> 12, n = o & 4095;
    const float* xr = x + (size_t)t * IN_F;
    const int*   wr2 = wp + (size_t)n * (IN_F / 2);
    float acc = 0.f;
    for (int g = 0; g < 32; ++g) {
        float s = sc[n * 32 + g];
        float part = 0.f;
        for (int j = 0; j < 64; ++j) {
            int p = wr2[g * 64 + j];
            part += xr[g * 128 + 2 * j]     * (float)((p & 15) - 8);
            part += xr[g * 128 + 2 * j + 1] * (float)(((p >> 4) & 15) - 8);
        }
        acc += part * s;
    }
    out[o] = acc;
}

extern "C" void kernel_launch(void* const* d_in, const int* in_sizes, int n_in,
                              void* d_out, int out_size, void* d_ws, size_t ws_size,
                              hipStream_t stream) {
    const float* x  = (const float*)d_in[0];
    const int*   wp = (const int*)d_in[1];
    const float* sc = (const float*)d_in[2];
    float* out = (float*)d_out;

    const size_t xb_bytes = (size_t)TOKENS * IN_F * 2;   // 64 MiB
    const size_t wb_bytes = (size_t)OUT_F * IN_F * 2;    // 32 MiB

    if (ws_size >= xb_bytes + wb_bytes) {
        bf16* xb = (bf16*)d_ws;
        bf16* wb = (bf16*)((char*)d_ws + xb_bytes);
        prep_kernel<<<dim3(2048), dim3(256), 0, stream>>>(x, xb, wp, sc, wb);
        gemm_kernel<<<dim3((TOKENS / 256) * (OUT_F / 256)), dim3(512), 0, stream>>>(xb, wb, out);
    } else {
        naive_kernel<<<dim3((TOKENS * OUT_F) / 256), dim3(256), 0, stream>>>(x, wp, sc, out);
    }
}

// Round 4
// 454.155 us; speedup vs baseline: 1.0831x; 1.0831x over previous
//
#include <hip/hip_runtime.h>
#include <cstdint>
#include <cstddef>

// Problem constants: x[8192,4096]f32, Wp[4096,2048]i32(1 byte each),
// scales[4096,32]f32, group=128, out[8192,4096]f32.
#define TOKENS 8192
#define IN_F   4096
#define OUT_F  4096

typedef __bf16 bf16;
typedef bf16  bf16x8 __attribute__((ext_vector_type(8)));
typedef float f32x4  __attribute__((ext_vector_type(4)));

// ---------------- merged pre-pass: x f32->bf16 AND int4 W -> bf16 ----------------
// one-shot 24576 blocks (r2 config: measured non-gemm 222us vs 241 grid-stride)
__global__ void prep_kernel(const float* __restrict__ xin, bf16* __restrict__ xout,
                            const int* __restrict__ wp, const float* __restrict__ sc,
                            bf16* __restrict__ wout) {
    if (blockIdx.x < 16384) {
        size_t i = ((size_t)blockIdx.x * 256 + threadIdx.x) * 8;
        const float4* p = (const float4*)(xin + i);
        float4 a = p[0], b = p[1];
        bf16x8 r;
        r[0] = (bf16)a.x; r[1] = (bf16)a.y; r[2] = (bf16)a.z; r[3] = (bf16)a.w;
        r[4] = (bf16)b.x; r[5] = (bf16)b.y; r[6] = (bf16)b.z; r[7] = (bf16)b.w;
        *(bf16x8*)(xout + i) = r;
    } else {
        int t  = (blockIdx.x - 16384) * 256 + threadIdx.x;
        int j0 = t << 2;
        int n  = j0 >> 11;
        int g  = (j0 & 2047) >> 6;
        float s = sc[(n << 5) + g];
        int4 p = *(const int4*)(wp + j0);
        bf16x8 r;
        r[0] = (bf16)((float)((p.x & 15) - 8) * s);
        r[1] = (bf16)((float)(((p.x >> 4) & 15) - 8) * s);
        r[2] = (bf16)((float)((p.y & 15) - 8) * s);
        r[3] = (bf16)((float)(((p.y >> 4) & 15) - 8) * s);
        r[4] = (bf16)((float)((p.z & 15) - 8) * s);
        r[5] = (bf16)((float)(((p.z >> 4) & 15) - 8) * s);
        r[6] = (bf16)((float)((p.w & 15) - 8) * s);
        r[7] = (bf16)((float)(((p.w >> 4) & 15) - 8) * s);
        *(bf16x8*)(wout + ((size_t)j0 << 1)) = r;
    }
}

// ---------------- main GEMM: 256x256 tile, BK=64, 4-phase/K-tile, 16x16x32 MFMA ----------------
// r2 structure (proven: 222us, 0 conflicts) + B-qc0 next-tile prefetch at ph3.
// Phase read balance 8/4/8/4 (was 12/4/8/0): MM(0,0)'s post-barrier lgkm critical path
// shrinks from ~9 outstanding reads to ~1 (its B operands were read last phase, after
// the tile vmcnt proved them landed).
//
// Region read phase: A0 {rows 0-63,128-191}: ph0 | B0 {row&32==0}: ph0 (PREFETCHED ph3
// of prev tile) | B1 {row&32==1}: ph1 | A1 {rows 64-127,192-255}: ph2
// Stage slots: ph0: B1(next, other buf) | ph1: A1(next, other buf) |
//              ph2: A0(tile+2, this buf) | ph3: B0(tile+2, this buf) + vmcnt(4)
// Prefetch safety: B0(next) staged >=2 tiles ago, landed by this vmcnt (it leaves only
// the 4 newest loads = A0/B0 of tile+2 in flight); region not rewritten until ph3 of
// the NEXT tile -> RAW and WAR both barrier-ordered, no latency assumptions.

#define GLL(src, dst) __builtin_amdgcn_global_load_lds( \
    (const __attribute__((address_space(1))) void*)(src), \
    (__attribute__((address_space(3))) void*)(dst), 16, 0, 0)
#define BARX() { __builtin_amdgcn_s_barrier(); __builtin_amdgcn_sched_barrier(0); }

__global__ __launch_bounds__(512, 2)
void gemm_kernel(const bf16* __restrict__ A, const bf16* __restrict__ B,
                 float* __restrict__ C) {
    __shared__ char smem[131072] __attribute__((aligned(128)));

    const int tid  = threadIdx.x;
    const int lane = tid & 63;
    const int w    = tid >> 6;
    const int wr   = w >> 2, wc = w & 3;
    const int lrow = lane >> 3;             // row within the wave's 8-row stage block
    const int gsw  = (lane & 7) ^ lrow;     // pre-swizzled global chunk within 128B row

    // bijective XCD swizzle (512 % 8 == 0)
    const int wg = ((blockIdx.x & 7) << 6) | (blockIdx.x >> 3);
    const int mt = wg >> 4;                 // 32 M-tiles
    const int nt = wg & 15;                 // 16 N-tiles

    const char* Abase = (const char*)A + (size_t)(mt * 256) * (IN_F * 2);
    const char* Bbase = (const char*)B + (size_t)(nt * 256) * (IN_F * 2);

    const char* gA[4];
#pragma unroll
    for (int t = 0; t < 4; ++t)
        gA[t] = Abase + (size_t)(t * 64 + w * 8 + lrow) * (IN_F * 2) + gsw * 16;
    const int rb = (w >> 2) * 64 + (w & 3) * 8;
    const int brow0 = rb, brow1 = rb + 128, brow2 = rb + 32, brow3 = rb + 160;
    const char* gB[4];
    gB[0] = Bbase + (size_t)(brow0 + lrow) * (IN_F * 2) + gsw * 16;
    gB[1] = Bbase + (size_t)(brow1 + lrow) * (IN_F * 2) + gsw * 16;
    gB[2] = Bbase + (size_t)(brow2 + lrow) * (IN_F * 2) + gsw * 16;
    gB[3] = Bbase + (size_t)(brow3 + lrow) * (IN_F * 2) + gsw * 16;

    char* const sm = smem;
    // wave-uniform LDS dest bases (HW adds lane*16)
#define ST_A0(b, kt) { GLL(gA[0] + (kt) * 128, sm + (b) * 65536 +     0 + w * 1024); \
                       GLL(gA[2] + (kt) * 128, sm + (b) * 65536 + 16384 + w * 1024); }
#define ST_A1(b, kt) { GLL(gA[1] + (kt) * 128, sm + (b) * 65536 +  8192 + w * 1024); \
                       GLL(gA[3] + (kt) * 128, sm + (b) * 65536 + 24576 + w * 1024); }
#define ST_B0(b, kt) { GLL(gB[0] + (kt) * 128, sm + (b) * 65536 + 32768 + brow0 * 128); \
                       GLL(gB[1] + (kt) * 128, sm + (b) * 65536 + 32768 + brow1 * 128); }
#define ST_B1(b, kt) { GLL(gB[2] + (kt) * 128, sm + (b) * 65536 + 32768 + brow2 * 128); \
                       GLL(gB[3] + (kt) * 128, sm + (b) * 65536 + 32768 + brow3 * 128); }

    const int m_lane = lane & 15, quad = lane >> 4, sw = m_lane & 7;
    const bf16x8* pA0 = (const bf16x8*)sm;
    const bf16x8* pB0 = (const bf16x8*)(sm + 32768);
    const bf16x8* pA1 = (const bf16x8*)(sm + 65536);
    const bf16x8* pB1 = (const bf16x8*)(sm + 98304);

    f32x4 acc[8][4];
#pragma unroll
    for (int i = 0; i < 8; ++i)
#pragma unroll
        for (int j = 0; j < 4; ++j) acc[i][j] = (f32x4)0.0f;

    // prologue: tile0 fully; tile1's A0/B0; leave the 2 newest half-tiles in flight
    ST_A0(0, 0); ST_B0(0, 0); ST_B1(0, 0); ST_A1(0, 0);
    ST_A0(1, 1); ST_B0(1, 1);
    asm volatile("s_waitcnt vmcnt(4)" ::: "memory");
    __builtin_amdgcn_s_barrier();

#define LDA(dst, PA, qr) \
    { _Pragma("unroll") for (int i = 0; i < 4; ++i) { \
        _Pragma("unroll") for (int kh = 0; kh < 2; ++kh) { \
            dst[i][kh] = (PA)[(wr * 128 + ((qr) * 4 + i) * 16 + m_lane) * 8 + ((kh * 4 + quad) ^ sw)]; } } }
#define LDBq(dst, PB, qc) \
    { _Pragma("unroll") for (int j = 0; j < 2; ++j) { \
        _Pragma("unroll") for (int kh = 0; kh < 2; ++kh) { \
            dst[j][kh] = (PB)[(wc * 64 + ((qc) * 2 + j) * 16 + m_lane) * 8 + ((kh * 4 + quad) ^ sw)]; } } }
#define MMq(afv, bv, qr, qc) \
    { __builtin_amdgcn_s_setprio(1); \
      _Pragma("unroll") for (int i = 0; i < 4; ++i) { \
        _Pragma("unroll") for (int j = 0; j < 2; ++j) { \
          _Pragma("unroll") for (int kh = 0; kh < 2; ++kh) { \
            acc[(qr) * 4 + i][(qc) * 2 + j] = __builtin_amdgcn_mfma_f32_16x16x32_bf16( \
                afv[i][kh], bv[j][kh], acc[(qr) * 4 + i][(qc) * 2 + j], 0, 0, 0); } } } \
      __builtin_amdgcn_s_setprio(0); }

    bf16x8 bq0[2][2], bq1[2][2];
    LDBq(bq0, pB0, 0);                         // prefetch tile0's qc0 B-frags

    for (int it = 0; it < 32; ++it) {
        const int kt0 = 2 * it;
        const int kt1 = kt0 + 1;
        const bool more = (it < 31);
        {   // ---- tile kt0 from buf0 ----
            bf16x8 af0[4][2], af1[4][2];
            LDA(af0, pA0, 0);                  // ph0: 8 ds_read_b128 (bq0 pre-loaded)
            ST_B1(1, kt1);                     //   buf1.B1 for tile kt1
            BARX(); MMq(af0, bq0, 0, 0);
            LDBq(bq1, pB0, 1);                 // ph1: 4 ds_read_b128
            ST_A1(1, kt1);                     //   buf1.A1
            BARX(); MMq(af0, bq1, 0, 1);
            LDA(af1, pA0, 1);                  // ph2: 8 ds_read_b128
            if (more) ST_A0(0, kt0 + 2);       //   buf0.A0 (read-drained at ph0)
            BARX(); MMq(af1, bq0, 1, 0);
            if (more) {                        // ph3
                ST_B0(0, kt0 + 2);
                asm volatile("s_waitcnt vmcnt(4)" ::: "memory");
            } else {
                asm volatile("s_waitcnt vmcnt(0)" ::: "memory");
            }
            LDBq(bq0, pB1, 0);                 //   prefetch tile kt1's qc0 (landed: see hdr)
            BARX(); MMq(af1, bq1, 1, 1);
        }
        {   // ---- tile kt1 from buf1 ----
            bf16x8 af0[4][2], af1[4][2];
            LDA(af0, pA1, 0);                  // ph0: 8 reads
            if (more) ST_B1(0, kt1 + 1);       //   buf0.B1 for tile kt1+1
            BARX(); MMq(af0, bq0, 0, 0);
            LDBq(bq1, pB1, 1);                 // ph1
            if (more) ST_A1(0, kt1 + 1);       //   buf0.A1
            BARX(); MMq(af0, bq1, 0, 1);
            LDA(af1, pA1, 1);                  // ph2
            if (more) ST_A0(1, kt1 + 2);       //   buf1.A0
            BARX(); MMq(af1, bq0, 1, 0);
            if (more) {                        // ph3
                ST_B0(1, kt1 + 2);
                asm volatile("s_waitcnt vmcnt(4)" ::: "memory");
                LDBq(bq0, pB0, 0);             //   prefetch tile kt1+1's qc0
            }
            BARX(); MMq(af1, bq1, 1, 1);
        }
    }

    // epilogue: C/D layout col=lane&15, row=quad*4+reg (m89-verified)
    const size_t crow0 = (size_t)(mt * 256 + wr * 128 + quad * 4) * OUT_F
                       + (size_t)(nt * 256 + wc * 64 + m_lane);
#pragma unroll
    for (int i = 0; i < 8; ++i)
#pragma unroll
        for (int r = 0; r < 4; ++r) {
            float* cp = C + crow0 + (size_t)(i * 16 + r) * OUT_F;
#pragma unroll
            for (int j = 0; j < 4; ++j) cp[j * 16] = acc[i][j][r];
        }
}

// ---------------- fallback (only if ws too small): slow but correct ----------------
__global__ void naive_kernel(const float* __restrict__ x, const int* __restrict__ wp,
                             const float* __restrict__ sc, float* __restrict__ out) {
    int o = blockIdx.x * 256 + threadIdx.x;
    int t = o >> 12, n = o & 4095;
    const float* xr = x + (size_t)t * IN_F;
    const int*   wr2 = wp + (size_t)n * (IN_F / 2);
    float acc = 0.f;
    for (int g = 0; g < 32; ++g) {
        float s = sc[n * 32 + g];
        float part = 0.f;
        for (int j = 0; j < 64; ++j) {
            int p = wr2[g * 64 + j];
            part += xr[g * 128 + 2 * j]     * (float)((p & 15) - 8);
            part += xr[g * 128 + 2 * j + 1] * (float)(((p >> 4) & 15) - 8);
        }
        acc += part * s;
    }
    out[o] = acc;
}

extern "C" void kernel_launch(void* const* d_in, const int* in_sizes, int n_in,
                              void* d_out, int out_size, void* d_ws, size_t ws_size,
                              hipStream_t stream) {
    const float* x  = (const float*)d_in[0];
    const int*   wp = (const int*)d_in[1];
    const float* sc = (const float*)d_in[2];
    float* out = (float*)d_out;

    const size_t xb_bytes = (size_t)TOKENS * IN_F * 2;   // 64 MiB
    const size_t wb_bytes = (size_t)OUT_F * IN_F * 2;    // 32 MiB

    if (ws_size >= xb_bytes + wb_bytes) {
        bf16* xb = (bf16*)d_ws;
        bf16* wb = (bf16*)((char*)d_ws + xb_bytes);
        prep_kernel<<<dim3(16384 + 8192), dim3(256), 0, stream>>>(x, xb, wp, sc, wb);
        gemm_kernel<<<dim3((TOKENS / 256) * (OUT_F / 256)), dim3(512), 0, stream>>>(xb, wb, out);
    } else {
        naive_kernel<<<dim3((TOKENS * OUT_F) / 256), dim3(256), 0, stream>>>(x, wp, sc, out);
    }
}